// Round 1
// baseline (225.078 us; speedup 1.0000x reference)
//
#include <hip/hip_runtime.h>
#include <math.h>

#define GN 16

__global__ __launch_bounds__(256) void kilonerf_fwd(
    const float* __restrict__ xg, const float* __restrict__ dg,
    const float* __restrict__ l1w, const float* __restrict__ l1b,
    const float* __restrict__ l2w, const float* __restrict__ l2b,
    const float* __restrict__ l3w, const float* __restrict__ l3b,
    const float* __restrict__ l4w, const float* __restrict__ l4b,
    const float* __restrict__ l5w, const float* __restrict__ l5b,
    float* __restrict__ out, int P)
{
    const int tid = threadIdx.x;
    const int sub = tid >> 5;          // which point within the block (0..7)
    const int o   = tid & 31;          // neuron index within 32-wide layers
    const int p   = blockIdx.x * 8 + sub;
    if (p >= P) return;

    const float x0 = xg[p*3+0], x1 = xg[p*3+1], x2 = xg[p*3+2];
    const float d0 = dg[p*3+0], d1 = dg[p*3+1], d2 = dg[p*3+2];

    // idx = clip(trunc(x / (SCALE/N) + N/2), 0, N-1)  -- trunc toward zero like astype(int32)
    int ix = (int)(x0 / 0.1875f + 8.0f); ix = ix < 0 ? 0 : (ix > 15 ? 15 : ix);
    int iy = (int)(x1 / 0.1875f + 8.0f); iy = iy < 0 ? 0 : (iy > 15 ? 15 : iy);
    int iz = (int)(x2 / 0.1875f + 8.0f); iz = iz < 0 ? 0 : (iz > 15 ? 15 : iz);
    const int cell = (ix*GN + iy)*GN + iz;

    // positional encodings: [v, sin(2^0 v), cos(2^0 v), sin(2^1 v), cos(2^1 v), ...]
    auto embx = [&](int m)->float {
        if (m == 0) return x0; if (m == 1) return x1; if (m == 2) return x2;
        int t = m - 3; int j = t / 6; int rem = t - j*6; int comp = rem % 3;
        float v = (comp == 0) ? x0 : ((comp == 1) ? x1 : x2);
        float s = ldexpf(v, j);              // exact 2^j * v
        return (rem < 3) ? sinf(s) : cosf(s);
    };
    auto embd = [&](int m)->float {
        if (m == 0) return d0; if (m == 1) return d1; if (m == 2) return d2;
        int t = m - 3; int j = t / 6; int rem = t - j*6; int comp = rem % 3;
        float v = (comp == 0) ? d0 : ((comp == 1) ? d1 : d2);
        float s = ldexpf(v, j);
        return (rem < 3) ? sinf(s) : cosf(s);
    };
    const float e_lo = embx(o);                         // emb_x[o]
    const float e_hi = (o + 32 < 63) ? embx(o + 32) : 0.0f;  // emb_x[o+32]
    const float ed   = (o < 27) ? embd(o) : 0.0f;       // emb_d[o]

    // ---- L1: 63 -> 32, relu ----
    const float* w1 = l1w + cell*2016;
    float acc = l1b[cell*32 + o];
    #pragma unroll
    for (int i = 0; i < 32; ++i) acc = fmaf(__shfl(e_lo, i, 32), w1[i*32 + o], acc);
    #pragma unroll
    for (int i = 0; i < 31; ++i) acc = fmaf(__shfl(e_hi, i, 32), w1[(i+32)*32 + o], acc);
    const float h1 = fmaxf(acc, 0.0f);

    // ---- L2: 32 -> 33, relu; neuron 32 is density ----
    const float* w2 = l2w + cell*1056;
    float acc2 = l2b[cell*33 + o];
    #pragma unroll
    for (int i = 0; i < 32; ++i) acc2 = fmaf(__shfl(h1, i, 32), w2[i*33 + o], acc2);
    const float h2 = fmaxf(acc2, 0.0f);
    float dp = h1 * w2[o*33 + 32];
    #pragma unroll
    for (int m = 16; m >= 1; m >>= 1) dp += __shfl_xor(dp, m, 32);
    const float density = fmaxf(dp + l2b[cell*33 + 32], 0.0f);

    // ---- L3: 32 -> 32, no activation ----
    const float* w3 = l3w + cell*1024;
    float acc3 = l3b[cell*32 + o];
    #pragma unroll
    for (int i = 0; i < 32; ++i) acc3 = fmaf(__shfl(h2, i, 32), w3[i*32 + o], acc3);
    const float h3 = acc3;

    // ---- L4: concat(h3[32], emb_d[27]) = 59 -> 32, relu ----
    const float* w4 = l4w + cell*1888;
    float acc4 = l4b[cell*32 + o];
    #pragma unroll
    for (int i = 0; i < 32; ++i) acc4 = fmaf(__shfl(h3, i, 32), w4[i*32 + o], acc4);
    #pragma unroll
    for (int i = 0; i < 27; ++i) acc4 = fmaf(__shfl(ed, i, 32), w4[(32+i)*32 + o], acc4);
    const float h4 = fmaxf(acc4, 0.0f);

    // ---- L5: 32 -> 3, sigmoid ----
    const float* w5 = l5w + cell*96;
    float c0 = h4 * w5[o*3 + 0];
    float c1 = h4 * w5[o*3 + 1];
    float c2 = h4 * w5[o*3 + 2];
    #pragma unroll
    for (int m = 16; m >= 1; m >>= 1) {
        c0 += __shfl_xor(c0, m, 32);
        c1 += __shfl_xor(c1, m, 32);
        c2 += __shfl_xor(c2, m, 32);
    }
    c0 += l5b[cell*3 + 0]; c1 += l5b[cell*3 + 1]; c2 += l5b[cell*3 + 2];

    const bool mask = (fabsf(x0) < 1.5f) && (fabsf(x1) < 1.5f) && (fabsf(x2) < 1.5f);
    if (o < 3) {
        float cv = (o == 0) ? c0 : ((o == 1) ? c1 : c2);
        float col = 1.0f / (1.0f + expf(-cv));
        out[p*3 + o] = mask ? col : 0.0f;
    }
    if (o == 0) {
        out[(size_t)P*3 + p] = mask ? density : 0.0f;
    }
}

extern "C" void kernel_launch(void* const* d_in, const int* in_sizes, int n_in,
                              void* d_out, int out_size, void* d_ws, size_t ws_size,
                              hipStream_t stream) {
    const float* x   = (const float*)d_in[0];
    const float* d   = (const float*)d_in[1];
    const float* l1w = (const float*)d_in[2];
    const float* l1b = (const float*)d_in[3];
    const float* l2w = (const float*)d_in[4];
    const float* l2b = (const float*)d_in[5];
    const float* l3w = (const float*)d_in[6];
    const float* l3b = (const float*)d_in[7];
    const float* l4w = (const float*)d_in[8];
    const float* l4b = (const float*)d_in[9];
    const float* l5w = (const float*)d_in[10];
    const float* l5b = (const float*)d_in[11];
    float* out = (float*)d_out;

    const int P = in_sizes[0] / 3;           // 32768
    const int blocks = (P + 7) / 8;          // 8 points per 256-thread block
    kilonerf_fwd<<<blocks, 256, 0, stream>>>(x, d, l1w, l1b, l2w, l2b, l3w, l3b,
                                             l4w, l4b, l5w, l5b, out, P);
}

// Round 2
// 169.434 us; speedup vs baseline: 1.3284x; 1.3284x over previous
//
#include <hip/hip_runtime.h>
#include <math.h>

#define GN 16
#define NCELL 4096

// ---- workspace layout (ints) ----
// cell[P]      @ 0
// order[P]     @ P
// hist[4096]   @ 2P
// offs[4096]   @ 2P + 4096
// cursor[4096] @ 2P + 8192
// total        @ 2P + 12288

__device__ __forceinline__ int cell_of(float x0, float x1, float x2) {
    int ix = (int)(x0 / 0.1875f + 8.0f); ix = ix < 0 ? 0 : (ix > 15 ? 15 : ix);
    int iy = (int)(x1 / 0.1875f + 8.0f); iy = iy < 0 ? 0 : (iy > 15 ? 15 : iy);
    int iz = (int)(x2 / 0.1875f + 8.0f); iz = iz < 0 ? 0 : (iz > 15 ? 15 : iz);
    return (ix * GN + iy) * GN + iz;
}

__global__ void k_zero_hist(int* hist) {
    int t = blockIdx.x * blockDim.x + threadIdx.x;
    if (t < NCELL) hist[t] = 0;
}

// classify: cell id, mask; masked points get zero outputs immediately
__global__ void k_classify(const float* __restrict__ xg, float* __restrict__ out,
                           int* __restrict__ cell, int* __restrict__ hist, int P) {
    int p = blockIdx.x * blockDim.x + threadIdx.x;
    if (p >= P) return;
    float x0 = xg[p*3+0], x1 = xg[p*3+1], x2 = xg[p*3+2];
    bool mask = (fabsf(x0) < 1.5f) && (fabsf(x1) < 1.5f) && (fabsf(x2) < 1.5f);
    if (mask) {
        int c = cell_of(x0, x1, x2);
        cell[p] = c;
        atomicAdd(&hist[c], 1);
    } else {
        cell[p] = -1;
        out[p*3+0] = 0.0f; out[p*3+1] = 0.0f; out[p*3+2] = 0.0f;
        out[(size_t)P*3 + p] = 0.0f;
    }
}

// single-block exclusive scan of hist[4096] -> offs, cursor; total count
__global__ __launch_bounds__(1024) void k_scan(const int* __restrict__ hist,
                                               int* __restrict__ offs,
                                               int* __restrict__ cursor,
                                               int* __restrict__ total) {
    __shared__ int s[1024];
    const int t = threadIdx.x;
    const int base = t * 4;
    int a0 = hist[base+0], a1 = hist[base+1], a2 = hist[base+2], a3 = hist[base+3];
    int sum = a0 + a1 + a2 + a3;
    s[t] = sum;
    __syncthreads();
    #pragma unroll
    for (int off = 1; off < 1024; off <<= 1) {
        int v = (t >= off) ? s[t - off] : 0;
        __syncthreads();
        s[t] += v;
        __syncthreads();
    }
    int excl = s[t] - sum;              // exclusive prefix of this thread's 4 entries
    int e0 = excl, e1 = e0 + a0, e2 = e1 + a1, e3 = e2 + a2;
    offs[base+0] = e0; offs[base+1] = e1; offs[base+2] = e2; offs[base+3] = e3;
    cursor[base+0] = e0; cursor[base+1] = e1; cursor[base+2] = e2; cursor[base+3] = e3;
    if (t == 1023) *total = s[1023];
}

__global__ void k_scatter(const int* __restrict__ cell, int* __restrict__ cursor,
                          int* __restrict__ order, int P) {
    int p = blockIdx.x * blockDim.x + threadIdx.x;
    if (p >= P) return;
    int c = cell[p];
    if (c >= 0) {
        int pos = atomicAdd(&cursor[c], 1);
        order[pos] = p;
    }
}

// main MLP kernel over cell-sorted unmasked points; 32 lanes per point
__global__ __launch_bounds__(256) void kilonerf_fwd(
    const float* __restrict__ xg, const float* __restrict__ dg,
    const float* __restrict__ l1w, const float* __restrict__ l1b,
    const float* __restrict__ l2w, const float* __restrict__ l2b,
    const float* __restrict__ l3w, const float* __restrict__ l3b,
    const float* __restrict__ l4w, const float* __restrict__ l4b,
    const float* __restrict__ l5w, const float* __restrict__ l5b,
    const int* __restrict__ order, const int* __restrict__ cellArr,
    const int* __restrict__ total,
    float* __restrict__ out, int P)
{
    const int tid = threadIdx.x;
    const int sub = tid >> 5;
    const int o   = tid & 31;
    const int s   = blockIdx.x * 8 + sub;   // sorted position
    const int n   = *total;
    if (s >= n) return;
    const int p    = order[s];
    const int cell = cellArr[p];

    const float x0 = xg[p*3+0], x1 = xg[p*3+1], x2 = xg[p*3+2];
    const float d0 = dg[p*3+0], d1 = dg[p*3+1], d2 = dg[p*3+2];

    auto embx = [&](int m)->float {
        if (m == 0) return x0; if (m == 1) return x1; if (m == 2) return x2;
        int t = m - 3; int j = t / 6; int rem = t - j*6; int comp = rem % 3;
        float v = (comp == 0) ? x0 : ((comp == 1) ? x1 : x2);
        float sarg = ldexpf(v, j);
        return (rem < 3) ? sinf(sarg) : cosf(sarg);
    };
    auto embd = [&](int m)->float {
        if (m == 0) return d0; if (m == 1) return d1; if (m == 2) return d2;
        int t = m - 3; int j = t / 6; int rem = t - j*6; int comp = rem % 3;
        float v = (comp == 0) ? d0 : ((comp == 1) ? d1 : d2);
        float sarg = ldexpf(v, j);
        return (rem < 3) ? sinf(sarg) : cosf(sarg);
    };
    const float e_lo = embx(o);
    const float e_hi = (o + 32 < 63) ? embx(o + 32) : 0.0f;
    const float ed   = (o < 27) ? embd(o) : 0.0f;

    // ---- L1: 63 -> 32, relu ----
    const float* w1 = l1w + cell*2016;
    float acc = l1b[cell*32 + o];
    #pragma unroll
    for (int i = 0; i < 32; ++i) acc = fmaf(__shfl(e_lo, i, 32), w1[i*32 + o], acc);
    #pragma unroll
    for (int i = 0; i < 31; ++i) acc = fmaf(__shfl(e_hi, i, 32), w1[(i+32)*32 + o], acc);
    const float h1 = fmaxf(acc, 0.0f);

    // ---- L2: 32 -> 33, relu; neuron 32 is density ----
    const float* w2 = l2w + cell*1056;
    float acc2 = l2b[cell*33 + o];
    #pragma unroll
    for (int i = 0; i < 32; ++i) acc2 = fmaf(__shfl(h1, i, 32), w2[i*33 + o], acc2);
    const float h2 = fmaxf(acc2, 0.0f);
    float dp = h1 * w2[o*33 + 32];
    #pragma unroll
    for (int m = 16; m >= 1; m >>= 1) dp += __shfl_xor(dp, m, 32);
    const float density = fmaxf(dp + l2b[cell*33 + 32], 0.0f);

    // ---- L3: 32 -> 32, no activation ----
    const float* w3 = l3w + cell*1024;
    float acc3 = l3b[cell*32 + o];
    #pragma unroll
    for (int i = 0; i < 32; ++i) acc3 = fmaf(__shfl(h2, i, 32), w3[i*32 + o], acc3);
    const float h3 = acc3;

    // ---- L4: concat(h3[32], emb_d[27]) = 59 -> 32, relu ----
    const float* w4 = l4w + cell*1888;
    float acc4 = l4b[cell*32 + o];
    #pragma unroll
    for (int i = 0; i < 32; ++i) acc4 = fmaf(__shfl(h3, i, 32), w4[i*32 + o], acc4);
    #pragma unroll
    for (int i = 0; i < 27; ++i) acc4 = fmaf(__shfl(ed, i, 32), w4[(32+i)*32 + o], acc4);
    const float h4 = fmaxf(acc4, 0.0f);

    // ---- L5: 32 -> 3, sigmoid ----
    const float* w5 = l5w + cell*96;
    float c0 = h4 * w5[o*3 + 0];
    float c1 = h4 * w5[o*3 + 1];
    float c2 = h4 * w5[o*3 + 2];
    #pragma unroll
    for (int m = 16; m >= 1; m >>= 1) {
        c0 += __shfl_xor(c0, m, 32);
        c1 += __shfl_xor(c1, m, 32);
        c2 += __shfl_xor(c2, m, 32);
    }
    c0 += l5b[cell*3 + 0]; c1 += l5b[cell*3 + 1]; c2 += l5b[cell*3 + 2];

    if (o < 3) {
        float cv = (o == 0) ? c0 : ((o == 1) ? c1 : c2);
        out[p*3 + o] = 1.0f / (1.0f + expf(-cv));
    }
    if (o == 0) {
        out[(size_t)P*3 + p] = density;
    }
}

extern "C" void kernel_launch(void* const* d_in, const int* in_sizes, int n_in,
                              void* d_out, int out_size, void* d_ws, size_t ws_size,
                              hipStream_t stream) {
    const float* x   = (const float*)d_in[0];
    const float* d   = (const float*)d_in[1];
    const float* l1w = (const float*)d_in[2];
    const float* l1b = (const float*)d_in[3];
    const float* l2w = (const float*)d_in[4];
    const float* l2b = (const float*)d_in[5];
    const float* l3w = (const float*)d_in[6];
    const float* l3b = (const float*)d_in[7];
    const float* l4w = (const float*)d_in[8];
    const float* l4b = (const float*)d_in[9];
    const float* l5w = (const float*)d_in[10];
    const float* l5b = (const float*)d_in[11];
    float* out = (float*)d_out;

    const int P = in_sizes[0] / 3;     // 32768
    int* ws = (int*)d_ws;
    int* cell   = ws;
    int* order  = ws + P;
    int* hist   = ws + 2*P;
    int* offs   = ws + 2*P + NCELL;
    int* cursor = ws + 2*P + 2*NCELL;
    int* total  = ws + 2*P + 3*NCELL;

    k_zero_hist<<<(NCELL + 255)/256, 256, 0, stream>>>(hist);
    k_classify<<<(P + 255)/256, 256, 0, stream>>>(x, out, cell, hist, P);
    k_scan<<<1, 1024, 0, stream>>>(hist, offs, cursor, total);
    k_scatter<<<(P + 255)/256, 256, 0, stream>>>(cell, cursor, order, P);
    kilonerf_fwd<<<(P + 7)/8, 256, 0, stream>>>(x, d, l1w, l1b, l2w, l2b, l3w, l3b,
                                                l4w, l4b, l5w, l5b,
                                                order, cell, total, out, P);
}